// Round 3
// baseline (289.954 us; speedup 1.0000x reference)
//
#include <hip/hip_runtime.h>
#include <hip/hip_bf16.h>

typedef __bf16 bf16x8 __attribute__((ext_vector_type(8)));
typedef __bf16 bf16x4 __attribute__((ext_vector_type(4)));
typedef float floatx4 __attribute__((ext_vector_type(4)));

// Async global->LDS DMA, 16 B per lane. Dest is wave-uniform base + lane*16.
__device__ __forceinline__ void async16(void* lds, const void* g) {
  __builtin_amdgcn_global_load_lds(
      (const __attribute__((address_space(1))) unsigned int*)g,
      (__attribute__((address_space(3))) unsigned int*)lds, 16, 0, 0);
}

// Fused preprocess: x->bf16 (blocks 0..2047), K->bf16 (2048..3071),
// V->Vt bf16 transpose (3072..4095), lsum zero (4096), out zero (4097..6144,
// needed because GEMM2 is K-split and accumulates with atomicAdd).
__global__ __launch_bounds__(256) void preprocess_kernel(
    const float* __restrict__ x, const float* __restrict__ Kp,
    const float* __restrict__ V, __bf16* __restrict__ xb,
    __bf16* __restrict__ Kb, __bf16* __restrict__ Vt,
    float* __restrict__ lsum, float* __restrict__ outz) {
  const int b = blockIdx.x;
  const int t = threadIdx.x;
  if (b < 2048) {
#pragma unroll
    for (int k = 0; k < 4; ++k) {
      const int i = b * 1024 + k * 256 + t;
      float4 v = ((const float4*)x)[i];
      bf16x4 o = {(__bf16)v.x, (__bf16)v.y, (__bf16)v.z, (__bf16)v.w};
      ((bf16x4*)xb)[i] = o;
    }
  } else if (b < 3072) {
#pragma unroll
    for (int k = 0; k < 4; ++k) {
      const int i = (b - 2048) * 1024 + k * 256 + t;
      float4 v = ((const float4*)Kp)[i];
      bf16x4 o = {(__bf16)v.x, (__bf16)v.y, (__bf16)v.z, (__bf16)v.w};
      ((bf16x4*)Kb)[i] = o;
    }
  } else if (b < 4096) {
    __shared__ float tile[64][65];
    const int bb = b - 3072;
    const int bx = bb & 63, by = bb >> 6;
    for (int i = t; i < 64 * 64; i += 256) {
      const int r = i >> 6, c = i & 63;
      tile[r][c] = V[(size_t)(bx * 64 + r) * 1024 + by * 64 + c];
    }
    __syncthreads();
    for (int i = t; i < 64 * 64; i += 256) {
      const int r = i >> 6, c = i & 63;
      Vt[(size_t)(by * 64 + r) * 4096 + bx * 64 + c] = (__bf16)tile[c][r];
    }
  } else if (b == 4096) {
#pragma unroll
    for (int k = 0; k < 8; ++k)
      ((floatx4*)lsum)[k * 256 + t] = floatx4{0.f, 0.f, 0.f, 0.f};
  } else {
    const size_t bb = b - 4097;
#pragma unroll
    for (int k = 0; k < 4; ++k)
      ((float4*)outz)[bb * 1024 + k * 256 + t] = float4{0.f, 0.f, 0.f, 0.f};
  }
}

// C = A (M x K bf16, row stride LD) x B (N rows of K bf16, row stride LD).
// BM=BN=256, BK=64. 512 threads = 8 waves (2M x 4N), wave-tile 128x64,
// acc[8][4] 16x16 fragments. m201-style 4-phase/K-tile schedule:
//   phase = (i-half, k-slice): q0=(i0-3,ks0) q1=(i4-7,ks0) q2=(i0-3,ks1) q3=(i4-7,ks1)
//   each phase: {ds_read 4-8 x b128 || stage ONE k-half (2 x global_load_lds)}
//               -> s_barrier -> lgkmcnt(0)+sched_barrier -> setprio(1) 16 MFMA
//               setprio(0) -> s_barrier.
// LDS 128 KiB = 2 bufs x {A kh0, A kh1, B kh0, B kh1} x 16 KiB. A k-half slot
// is read only in its 2 phases -> 4-half staging ring:
//   T.q0 -> A-kh1(T+1), T.q1 -> B-kh1(T+1), T.q2 -> A-kh0(T+2), T.q3 -> B-kh0(T+2)
// vmcnt(8) before the q1/q3 barriers (4 halves = 8 loads in flight; issue-to-use
// distance 4-5 phases). Never vmcnt(0) except the last tile. Tail: q1 of last
// tile -> vmcnt(0); q3 of tile NT-2 -> vmcnt(4).
// Swizzle (64B half-rows): element (row m, k-chunk q in 0..3 of the 32-k half)
// lives at byte (m>>1)*128 + ((((m&1)*4+q) ^ ((m>>1)&7))*16). Each aligned
// 8-lane beat of a frag ds_read_b128 hits 8 distinct bank-quads (verified by
// hand). Writes: global_load_lds dest is LINEAR (t*16, +8192 for rows+128);
// the swizzle is applied to the per-lane GLOBAL source address:
//   v=(t&7)^((t>>3)&7); srcrow=2*(t>>3)+(v>>2); srck=(v&3)*8.
// Grid: mt-FASTEST within XCD (R1-proven L2 locality): g=id&7, s=id>>3,
//   ks=s%SPL, r=s/SPL, mt=g*MTX+(r%MTX), nt=r/MTX. SPL = K-split slices.
// MODE 0: P = exp(min(dot/32,30)) -> bf16 Cb + fused row-sum atomicAdd.
// MODE 1: atomicAdd(out, dot/lsum[m]) (K-split partial; linear in 1/lsum).
template <int MODE, int LD, int KR, int NS, int MTX, int SPL>
__global__ __launch_bounds__(512, 2) void gemm_kernel(const __bf16* __restrict__ A,
                                                      const __bf16* __restrict__ B,
                                                      __bf16* __restrict__ Cb,
                                                      float* __restrict__ Cf,
                                                      float* __restrict__ lsum) {
  constexpr int NT = KR / 64;
  __shared__ char lds[131072];

  const int t = threadIdx.x;
  const int lane = t & 63;
  const int w = t >> 6;
  const int wm = w >> 2;  // 0..1 (A 128-row band)
  const int wn = w & 3;   // 0..3 (B 64-row band)

  const int id = blockIdx.x;
  const int g = id & 7;
  const int s = id >> 3;
  const int ks = s % SPL;
  const int r2 = s / SPL;
  const int mt = g * MTX + (r2 % MTX);
  const int nt = r2 / MTX;
  const int m0 = mt * 256;
  const int n0 = nt * 256;
  const size_t koff = (size_t)ks * KR;

  // staging source map (pre-swizzled global, linear LDS dest)
  const int v = (t & 7) ^ ((t >> 3) & 7);
  const int srow = 2 * (t >> 3) + (v >> 2);  // 0..127 (+128 via 2nd load)
  const int sk8 = (v & 3) * 8;
  const __bf16* aS = A + (size_t)(m0 + srow) * LD + koff + sk8;
  const __bf16* bS = B + (size_t)(n0 + srow) * LD + koff + sk8;
  const int t16 = t * 16;

  auto stageA = [&](int slot, int kElem) {
    const __bf16* p = aS + kElem;
    async16(lds + slot + t16, p);
    async16(lds + slot + 8192 + t16, p + (size_t)128 * LD);
  };
  auto stageB = [&](int slot, int kElem) {
    const __bf16* p = bS + kElem;
    async16(lds + slot + t16, p);
    async16(lds + slot + 8192 + t16, p + (size_t)128 * LD);
  };

  // fragment read offset: row rl=lane&15 within 16-row group, chunk qq=lane>>4
  const int rl = lane & 15;
  const int qq = lane >> 4;
  const int fo = (rl >> 1) * 128 + (((((rl & 1) << 2) | qq) ^ (rl >> 1)) << 4);
  const int aOff = wm * 8192 + fo;  // + i*1024 within A k-half slot (16 KiB)
  const int bOff = wn * 4096 + fo;  // + j*1024 within B k-half slot

  floatx4 acc[8][4] = {};

  // LDS slots (bytes): buf b: A-kh0 = b*65536, A-kh1 = +16384,
  //                    B-kh0 = +32768, B-kh1 = +49152.
  // prologue: t0 kh0, t0 kh1, t1 kh0 (12 loads); wait oldest 4 (t0 kh0).
  stageA(0, 0);          stageB(32768, 0);
  stageA(16384, 32);     stageB(49152, 32);
  stageA(65536, 64);     stageB(98304, 64);
  asm volatile("s_waitcnt vmcnt(8)" ::: "memory");
  __builtin_amdgcn_s_barrier();

  for (int T = 0; T < NT; ++T) {
    const int bas = (T & 1) << 16;
    const int oth = bas ^ 65536;
    const int kT = T * 64;
    bf16x8 aF[4], bF[4];

    // ---- q0: ks0, i-half0 ----
#pragma unroll
    for (int i = 0; i < 4; ++i) aF[i] = *(const bf16x8*)(lds + bas + aOff + i * 1024);
#pragma unroll
    for (int j = 0; j < 4; ++j) bF[j] = *(const bf16x8*)(lds + bas + 32768 + bOff + j * 1024);
    if (T + 1 < NT) stageA(oth + 16384, kT + 96);  // A-kh1(T+1)
    __builtin_amdgcn_s_barrier();
    asm volatile("s_waitcnt lgkmcnt(0)" ::: "memory");
    __builtin_amdgcn_sched_barrier(0);
    __builtin_amdgcn_s_setprio(1);
#pragma unroll
    for (int i = 0; i < 4; ++i)
#pragma unroll
      for (int j = 0; j < 4; ++j)
        acc[i][j] = __builtin_amdgcn_mfma_f32_16x16x32_bf16(aF[i], bF[j], acc[i][j], 0, 0, 0);
    __builtin_amdgcn_s_setprio(0);
    __builtin_amdgcn_s_barrier();

    // ---- q1: ks0, i-half1 ----
#pragma unroll
    for (int i = 0; i < 4; ++i) aF[i] = *(const bf16x8*)(lds + bas + aOff + 4096 + i * 1024);
    if (T + 1 < NT) stageB(oth + 49152, kT + 96);  // B-kh1(T+1)
    if (T == NT - 1) asm volatile("s_waitcnt vmcnt(0)" ::: "memory");
    else             asm volatile("s_waitcnt vmcnt(8)" ::: "memory");
    __builtin_amdgcn_s_barrier();
    asm volatile("s_waitcnt lgkmcnt(0)" ::: "memory");
    __builtin_amdgcn_sched_barrier(0);
    __builtin_amdgcn_s_setprio(1);
#pragma unroll
    for (int i = 0; i < 4; ++i)
#pragma unroll
      for (int j = 0; j < 4; ++j)
        acc[4 + i][j] = __builtin_amdgcn_mfma_f32_16x16x32_bf16(aF[i], bF[j], acc[4 + i][j], 0, 0, 0);
    __builtin_amdgcn_s_setprio(0);
    __builtin_amdgcn_s_barrier();

    // ---- q2: ks1, i-half0 ----
#pragma unroll
    for (int i = 0; i < 4; ++i) aF[i] = *(const bf16x8*)(lds + bas + 16384 + aOff + i * 1024);
#pragma unroll
    for (int j = 0; j < 4; ++j) bF[j] = *(const bf16x8*)(lds + bas + 49152 + bOff + j * 1024);
    if (T + 2 < NT) stageA(bas, kT + 128);  // A-kh0(T+2), slot free after q1
    __builtin_amdgcn_s_barrier();
    asm volatile("s_waitcnt lgkmcnt(0)" ::: "memory");
    __builtin_amdgcn_sched_barrier(0);
    __builtin_amdgcn_s_setprio(1);
#pragma unroll
    for (int i = 0; i < 4; ++i)
#pragma unroll
      for (int j = 0; j < 4; ++j)
        acc[i][j] = __builtin_amdgcn_mfma_f32_16x16x32_bf16(aF[i], bF[j], acc[i][j], 0, 0, 0);
    __builtin_amdgcn_s_setprio(0);
    __builtin_amdgcn_s_barrier();

    // ---- q3: ks1, i-half1 ----
#pragma unroll
    for (int i = 0; i < 4; ++i) aF[i] = *(const bf16x8*)(lds + bas + 16384 + aOff + 4096 + i * 1024);
    if (T + 2 < NT) stageB(bas + 32768, kT + 128);  // B-kh0(T+2)
    if (T + 2 < NT)      asm volatile("s_waitcnt vmcnt(8)" ::: "memory");
    else if (T + 1 < NT) asm volatile("s_waitcnt vmcnt(4)" ::: "memory");
    __builtin_amdgcn_s_barrier();
    asm volatile("s_waitcnt lgkmcnt(0)" ::: "memory");
    __builtin_amdgcn_sched_barrier(0);
    __builtin_amdgcn_s_setprio(1);
#pragma unroll
    for (int i = 0; i < 4; ++i)
#pragma unroll
      for (int j = 0; j < 4; ++j)
        acc[4 + i][j] = __builtin_amdgcn_mfma_f32_16x16x32_bf16(aF[i], bF[j], acc[4 + i][j], 0, 0, 0);
    __builtin_amdgcn_s_setprio(0);
    __builtin_amdgcn_s_barrier();
  }

  // C/D layout: col = lane&15 (N), row = (lane>>4)*4 + reg (M within 16)
  const int cmB = wm * 128 + ((lane >> 4) << 2);
  const int cn = n0 + wn * 64 + (lane & 15);
  if (MODE == 0) {
#pragma unroll
    for (int i = 0; i < 8; ++i)
#pragma unroll
      for (int r = 0; r < 4; ++r) {
        const int m = m0 + cmB + i * 16 + r;
        float rs = 0.f;
#pragma unroll
        for (int j = 0; j < 4; ++j) {
          const float e = __expf(fminf(acc[i][j][r] * 0.03125f, 30.0f));
          rs += e;
          Cb[(size_t)m * NS + cn + j * 16] = (__bf16)e;
        }
        rs += __shfl_xor(rs, 1, 64);
        rs += __shfl_xor(rs, 2, 64);
        rs += __shfl_xor(rs, 4, 64);
        rs += __shfl_xor(rs, 8, 64);
        if ((lane & 15) == 0) atomicAdd(&lsum[m], rs);
      }
  } else {
#pragma unroll
    for (int i = 0; i < 8; ++i)
#pragma unroll
      for (int r = 0; r < 4; ++r) {
        const int m = m0 + cmB + i * 16 + r;
        const float inv = 1.0f / lsum[m];
#pragma unroll
        for (int j = 0; j < 4; ++j)
          atomicAdd(&Cf[(size_t)m * NS + cn + j * 16], acc[i][j][r] * inv);
      }
  }
}

extern "C" void kernel_launch(void* const* d_in, const int* in_sizes, int n_in,
                              void* d_out, int out_size, void* d_ws, size_t ws_size,
                              hipStream_t stream) {
  const float* x = (const float*)d_in[0];  // [8192][1024] fp32
  const float* K = (const float*)d_in[1];  // [4096][1024] fp32
  const float* V = (const float*)d_in[2];  // [4096][1024] fp32
  float* out = (float*)d_out;              // [8192][1024] fp32

  char* ws = (char*)d_ws;
  __bf16* xb = (__bf16*)ws;                        // 16 MiB
  __bf16* Kb = (__bf16*)(ws + (16u << 20));        // 8 MiB
  __bf16* Vt = (__bf16*)(ws + (24u << 20));        // 8 MiB
  __bf16* P  = (__bf16*)(ws + (32u << 20));        // 64 MiB
  float*  l  = (float*)(ws + (96u << 20));         // 32 KiB

  preprocess_kernel<<<6145, 256, 0, stream>>>(x, K, V, xb, Kb, Vt, l, out);
  // P = exp(xb @ Kb^T / 32), fused row sums (M=8192 N=4096 K=1024), 512 blocks
  gemm_kernel<0, 1024, 1024, 4096, 4, 1><<<512, 512, 0, stream>>>(xb, Kb, P, nullptr, l);
  // out += (P @ Vt-rows)/l, K-split=2 (M=8192 N=1024 K=2x2048), 256 blocks
  gemm_kernel<1, 4096, 2048, 1024, 4, 2><<<256, 512, 0, stream>>>(P, Vt, nullptr, out, l);
}

// Round 4
// 287.216 us; speedup vs baseline: 1.0095x; 1.0095x over previous
//
#include <hip/hip_runtime.h>
#include <hip/hip_bf16.h>

typedef __bf16 bf16x8 __attribute__((ext_vector_type(8)));
typedef __bf16 bf16x4 __attribute__((ext_vector_type(4)));
typedef float floatx4 __attribute__((ext_vector_type(4)));

// Async global->LDS DMA, 16 B per lane. Dest is wave-uniform base + lane*16.
__device__ __forceinline__ void async16(void* lds, const void* g) {
  __builtin_amdgcn_global_load_lds(
      (const __attribute__((address_space(1))) unsigned int*)g,
      (__attribute__((address_space(3))) unsigned int*)lds, 16, 0, 0);
}

// Fused preprocess: x->bf16 (blocks 0..2047), K->bf16 (2048..3071),
// V->Vt bf16 transpose (3072..4095), lsum zero (4096), out zero (4097..6144,
// needed because GEMM2 is K-split and accumulates with atomicAdd).
__global__ __launch_bounds__(256) void preprocess_kernel(
    const float* __restrict__ x, const float* __restrict__ Kp,
    const float* __restrict__ V, __bf16* __restrict__ xb,
    __bf16* __restrict__ Kb, __bf16* __restrict__ Vt,
    float* __restrict__ lsum, float* __restrict__ outz) {
  const int b = blockIdx.x;
  const int t = threadIdx.x;
  if (b < 2048) {
#pragma unroll
    for (int k = 0; k < 4; ++k) {
      const int i = b * 1024 + k * 256 + t;
      float4 v = ((const float4*)x)[i];
      bf16x4 o = {(__bf16)v.x, (__bf16)v.y, (__bf16)v.z, (__bf16)v.w};
      ((bf16x4*)xb)[i] = o;
    }
  } else if (b < 3072) {
#pragma unroll
    for (int k = 0; k < 4; ++k) {
      const int i = (b - 2048) * 1024 + k * 256 + t;
      float4 v = ((const float4*)Kp)[i];
      bf16x4 o = {(__bf16)v.x, (__bf16)v.y, (__bf16)v.z, (__bf16)v.w};
      ((bf16x4*)Kb)[i] = o;
    }
  } else if (b < 4096) {
    __shared__ float tile[64][65];
    const int bb = b - 3072;
    const int bx = bb & 63, by = bb >> 6;
    for (int i = t; i < 64 * 64; i += 256) {
      const int r = i >> 6, c = i & 63;
      tile[r][c] = V[(size_t)(bx * 64 + r) * 1024 + by * 64 + c];
    }
    __syncthreads();
    for (int i = t; i < 64 * 64; i += 256) {
      const int r = i >> 6, c = i & 63;
      Vt[(size_t)(by * 64 + r) * 4096 + bx * 64 + c] = (__bf16)tile[c][r];
    }
  } else if (b == 4096) {
#pragma unroll
    for (int k = 0; k < 8; ++k)
      ((floatx4*)lsum)[k * 256 + t] = floatx4{0.f, 0.f, 0.f, 0.f};
  } else {
    const size_t bb = b - 4097;
#pragma unroll
    for (int k = 0; k < 4; ++k)
      ((float4*)outz)[bb * 1024 + k * 256 + t] = float4{0.f, 0.f, 0.f, 0.f};
  }
}

// C = A (M x K bf16, row stride LD) x B (N rows of K bf16, row stride LD).
// BM=BN=256, BK=64. 512 threads = 8 waves (2M x 4N), wave-tile 128x64,
// acc[8][4]. m201-faithful REGION schedule: ONE barrier per phase; a region
// contains {ds_read frags for NEXT region's MFMA || stage one k-half of a
// future tile || setprio(1) 16 MFMA setprio(0)}; counted vmcnt(6) at ends of
// regions q0/q2 only (tail 6->4->0, prologue vmcnt(8)). No sched_barrier, no
// lgkm asm: compiler emits counted lgkmcnt at first frag use (reads were
// issued a full region earlier), so LDS-read issue overlaps MFMA issue.
// Frag registers ping-pong statically: aA/aB alternate per region; bX=kh0,
// bY=kh1 (each read one region before first use, live for two regions).
// LDS 128 KiB = 2 bufs x {A-kh0,A-kh1,B-kh0,B-kh1} x 16 KiB; stage ring:
//   q0(T)->A-kh1(T+1), q1(T)->B-kh1(T+1), q2(T)->A-kh0(T+2), q3(T)->B-kh0(T+2)
// Hazard audit: every slot has >=2 barrier boundaries between last
// read-retirement (lgkm-drained before the consuming MFMA) and overwrite
// issue; every first-read is behind its vmcnt guard + barrier.
// Swizzle (proven, SQ_LDS_BANK_CONFLICT=0) identical to round 3: LDS dest
// linear t*16, global source pre-swizzled; frag offset fo as derived.
// Grid: mt-fastest within XCD; SPL = K-split slices.
// MODE 0: P = exp(min(dot/32,30)) -> bf16 Cb + fused row-sum atomicAdd.
// MODE 1: atomicAdd(out, dot/lsum[m]) (K-split partial; linear in 1/lsum).
template <int MODE, int LD, int KR, int NS, int MTX, int SPL>
__global__ __launch_bounds__(512, 2) void gemm_kernel(const __bf16* __restrict__ A,
                                                      const __bf16* __restrict__ B,
                                                      __bf16* __restrict__ Cb,
                                                      float* __restrict__ Cf,
                                                      float* __restrict__ lsum) {
  constexpr int NT = KR / 64;
  __shared__ char lds[131072];

  const int t = threadIdx.x;
  const int lane = t & 63;
  const int w = t >> 6;
  const int wm = w >> 2;  // 0..1 (A 128-row band)
  const int wn = w & 3;   // 0..3 (B 64-row band)

  const int id = blockIdx.x;
  const int g = id & 7;
  const int s = id >> 3;
  const int ks = s % SPL;
  const int r2 = s / SPL;
  const int mt = g * MTX + (r2 % MTX);
  const int nt = r2 / MTX;
  const int m0 = mt * 256;
  const int n0 = nt * 256;
  const size_t koff = (size_t)ks * KR;

  // staging source map (pre-swizzled global, linear LDS dest)
  const int v = (t & 7) ^ ((t >> 3) & 7);
  const int srow = 2 * (t >> 3) + (v >> 2);
  const int sk8 = (v & 3) * 8;
  const __bf16* aS = A + (size_t)(m0 + srow) * LD + koff + sk8;
  const __bf16* bS = B + (size_t)(n0 + srow) * LD + koff + sk8;
  const int t16 = t * 16;

  auto stageA = [&](int slot, int kElem) {
    const __bf16* p = aS + kElem;
    async16(lds + slot + t16, p);
    async16(lds + slot + 8192 + t16, p + (size_t)128 * LD);
  };
  auto stageB = [&](int slot, int kElem) {
    const __bf16* p = bS + kElem;
    async16(lds + slot + t16, p);
    async16(lds + slot + 8192 + t16, p + (size_t)128 * LD);
  };

  // fragment read offset
  const int rl = lane & 15;
  const int qq = lane >> 4;
  const int fo = (rl >> 1) * 128 + (((((rl & 1) << 2) | qq) ^ (rl >> 1)) << 4);
  const int aOff = wm * 8192 + fo;  // + i*1024 within a 16 KiB A k-half slot
  const int bOff = wn * 4096 + fo;  // + j*1024 within a 16 KiB B k-half slot

  floatx4 acc[8][4] = {};

  // LDS slots: buf b (b*65536): A-kh0 +0, A-kh1 +16384, B-kh0 +32768, B-kh1 +49152
  // prologue: kh0(0), kh1(0), kh0(1) in order; wait oldest 4 (kh0(0)).
  stageA(0, 0);          stageB(32768, 0);
  stageA(16384, 32);     stageB(49152, 32);
  stageA(65536, 64);     stageB(98304, 64);
  asm volatile("s_waitcnt vmcnt(8)" ::: "memory");
  __builtin_amdgcn_s_barrier();

  bf16x8 aA[4], aB[4], bX[4], bY[4];
  // pre-region reads: aA = A-kh0-h0(0), bX = B-kh0(0)
#pragma unroll
  for (int i = 0; i < 4; ++i) aA[i] = *(const bf16x8*)(lds + aOff + i * 1024);
#pragma unroll
  for (int j = 0; j < 4; ++j) bX[j] = *(const bf16x8*)(lds + 32768 + bOff + j * 1024);

  for (int T = 0; T < NT; ++T) {
    const int bas = (T & 1) << 16;
    const int oth = bas ^ 65536;
    const int kT = T * 64;

    // ---- region q0: read aB=A-kh0-h1(T); stage A-kh1(T+1); MFMA(aA,bX)->acc[0..3]
#pragma unroll
    for (int i = 0; i < 4; ++i) aB[i] = *(const bf16x8*)(lds + bas + aOff + 4096 + i * 1024);
    if (T + 1 < NT) stageA(oth + 16384, kT + 96);
    __builtin_amdgcn_s_setprio(1);
#pragma unroll
    for (int i = 0; i < 4; ++i)
#pragma unroll
      for (int j = 0; j < 4; ++j)
        acc[i][j] = __builtin_amdgcn_mfma_f32_16x16x32_bf16(aA[i], bX[j], acc[i][j], 0, 0, 0);
    __builtin_amdgcn_s_setprio(0);
    if (T + 1 < NT) asm volatile("s_waitcnt vmcnt(6)" ::: "memory");
    else            asm volatile("s_waitcnt vmcnt(0)" ::: "memory");
    __builtin_amdgcn_s_barrier();

    // ---- region q1: read aA=A-kh1-h0(T), bY=B-kh1(T); stage B-kh1(T+1); MFMA(aB,bX)->acc[4..7]
#pragma unroll
    for (int i = 0; i < 4; ++i) aA[i] = *(const bf16x8*)(lds + bas + 16384 + aOff + i * 1024);
#pragma unroll
    for (int j = 0; j < 4; ++j) bY[j] = *(const bf16x8*)(lds + bas + 49152 + bOff + j * 1024);
    if (T + 1 < NT) stageB(oth + 49152, kT + 96);
    __builtin_amdgcn_s_setprio(1);
#pragma unroll
    for (int i = 0; i < 4; ++i)
#pragma unroll
      for (int j = 0; j < 4; ++j)
        acc[4 + i][j] = __builtin_amdgcn_mfma_f32_16x16x32_bf16(aB[i], bX[j], acc[4 + i][j], 0, 0, 0);
    __builtin_amdgcn_s_setprio(0);
    __builtin_amdgcn_s_barrier();

    // ---- region q2: read aB=A-kh1-h1(T); stage A-kh0(T+2); MFMA(aA,bY)->acc[0..3]
#pragma unroll
    for (int i = 0; i < 4; ++i) aB[i] = *(const bf16x8*)(lds + bas + 16384 + aOff + 4096 + i * 1024);
    if (T + 2 < NT) stageA(bas, kT + 128);
    __builtin_amdgcn_s_setprio(1);
#pragma unroll
    for (int i = 0; i < 4; ++i)
#pragma unroll
      for (int j = 0; j < 4; ++j)
        acc[i][j] = __builtin_amdgcn_mfma_f32_16x16x32_bf16(aA[i], bY[j], acc[i][j], 0, 0, 0);
    __builtin_amdgcn_s_setprio(0);
    if (T + 2 < NT)      asm volatile("s_waitcnt vmcnt(6)" ::: "memory");
    else if (T + 1 < NT) asm volatile("s_waitcnt vmcnt(4)" ::: "memory");
    __builtin_amdgcn_s_barrier();

    // ---- region q3: read aA=A-kh0-h0(T+1), bX=B-kh0(T+1); stage B-kh0(T+2); MFMA(aB,bY)->acc[4..7]
    if (T + 1 < NT) {
#pragma unroll
      for (int i = 0; i < 4; ++i) aA[i] = *(const bf16x8*)(lds + oth + aOff + i * 1024);
#pragma unroll
      for (int j = 0; j < 4; ++j) bX[j] = *(const bf16x8*)(lds + oth + 32768 + bOff + j * 1024);
    }
    if (T + 2 < NT) stageB(bas + 32768, kT + 128);
    __builtin_amdgcn_s_setprio(1);
#pragma unroll
    for (int i = 0; i < 4; ++i)
#pragma unroll
      for (int j = 0; j < 4; ++j)
        acc[4 + i][j] = __builtin_amdgcn_mfma_f32_16x16x32_bf16(aB[i], bY[j], acc[4 + i][j], 0, 0, 0);
    __builtin_amdgcn_s_setprio(0);
    __builtin_amdgcn_s_barrier();
  }

  // C/D layout: col = lane&15 (N), row = (lane>>4)*4 + reg (M within 16)
  const int cmB = wm * 128 + ((lane >> 4) << 2);
  const int cn = n0 + wn * 64 + (lane & 15);
  if (MODE == 0) {
#pragma unroll
    for (int i = 0; i < 8; ++i)
#pragma unroll
      for (int r = 0; r < 4; ++r) {
        const int m = m0 + cmB + i * 16 + r;
        float rs = 0.f;
#pragma unroll
        for (int j = 0; j < 4; ++j) {
          const float e = __expf(fminf(acc[i][j][r] * 0.03125f, 30.0f));
          rs += e;
          Cb[(size_t)m * NS + cn + j * 16] = (__bf16)e;
        }
        rs += __shfl_xor(rs, 1, 64);
        rs += __shfl_xor(rs, 2, 64);
        rs += __shfl_xor(rs, 4, 64);
        rs += __shfl_xor(rs, 8, 64);
        if ((lane & 15) == 0) atomicAdd(&lsum[m], rs);
      }
  } else {
#pragma unroll
    for (int i = 0; i < 8; ++i)
#pragma unroll
      for (int r = 0; r < 4; ++r) {
        const int m = m0 + cmB + i * 16 + r;
        const float inv = 1.0f / lsum[m];
#pragma unroll
        for (int j = 0; j < 4; ++j)
          atomicAdd(&Cf[(size_t)m * NS + cn + j * 16], acc[i][j][r] * inv);
      }
  }
}

extern "C" void kernel_launch(void* const* d_in, const int* in_sizes, int n_in,
                              void* d_out, int out_size, void* d_ws, size_t ws_size,
                              hipStream_t stream) {
  const float* x = (const float*)d_in[0];  // [8192][1024] fp32
  const float* K = (const float*)d_in[1];  // [4096][1024] fp32
  const float* V = (const float*)d_in[2];  // [4096][1024] fp32
  float* out = (float*)d_out;              // [8192][1024] fp32

  char* ws = (char*)d_ws;
  __bf16* xb = (__bf16*)ws;                        // 16 MiB
  __bf16* Kb = (__bf16*)(ws + (16u << 20));        // 8 MiB
  __bf16* Vt = (__bf16*)(ws + (24u << 20));        // 8 MiB
  __bf16* P  = (__bf16*)(ws + (32u << 20));        // 64 MiB
  float*  l  = (float*)(ws + (96u << 20));         // 32 KiB

  preprocess_kernel<<<6145, 256, 0, stream>>>(x, K, V, xb, Kb, Vt, l, out);
  // P = exp(xb @ Kb^T / 32), fused row sums (M=8192 N=4096 K=1024), 512 blocks
  gemm_kernel<0, 1024, 1024, 4096, 4, 1><<<512, 512, 0, stream>>>(xb, Kb, P, nullptr, l);
  // out += (P @ Vt-rows)/l, K-split=2 (M=8192 N=1024 K=2x2048), 256 blocks
  gemm_kernel<1, 4096, 2048, 1024, 4, 2><<<256, 512, 0, stream>>>(P, Vt, nullptr, out, l);
}

// Round 5
// 260.791 us; speedup vs baseline: 1.1118x; 1.1013x over previous
//
#include <hip/hip_runtime.h>
#include <hip/hip_bf16.h>

typedef __bf16 bf16x8 __attribute__((ext_vector_type(8)));
typedef __bf16 bf16x4 __attribute__((ext_vector_type(4)));
typedef float floatx4 __attribute__((ext_vector_type(4)));

// Async global->LDS DMA, 16 B per lane. Dest is wave-uniform base + lane*16
// (HW takes firstlane of the LDS pointer); source is per-lane.
__device__ __forceinline__ void async16(void* lds, const void* g) {
  __builtin_amdgcn_global_load_lds(
      (const __attribute__((address_space(1))) unsigned int*)g,
      (__attribute__((address_space(3))) unsigned int*)lds, 16, 0, 0);
}

// Fused preprocess: x->bf16 (blocks 0..2047), K->bf16 (2048..3071),
// V->Vt bf16 transpose (3072..4095), lsum zero (block 4096).
// x/K conversion: 2x float4 loads -> 1x 16B bf16x8 store per iter.
__global__ __launch_bounds__(256) void preprocess_kernel(
    const float* __restrict__ x, const float* __restrict__ Kp,
    const float* __restrict__ V, __bf16* __restrict__ xb,
    __bf16* __restrict__ Kb, __bf16* __restrict__ Vt,
    float* __restrict__ lsum) {
  const int b = blockIdx.x;
  const int t = threadIdx.x;
  if (b < 2048) {
#pragma unroll
    for (int k = 0; k < 2; ++k) {
      const int i8 = b * 512 + k * 256 + t;  // bf16x8 units
      float4 va = ((const float4*)x)[2 * i8];
      float4 vb = ((const float4*)x)[2 * i8 + 1];
      bf16x8 o = {(__bf16)va.x, (__bf16)va.y, (__bf16)va.z, (__bf16)va.w,
                  (__bf16)vb.x, (__bf16)vb.y, (__bf16)vb.z, (__bf16)vb.w};
      ((bf16x8*)xb)[i8] = o;
    }
  } else if (b < 3072) {
#pragma unroll
    for (int k = 0; k < 2; ++k) {
      const int i8 = (b - 2048) * 512 + k * 256 + t;
      float4 va = ((const float4*)Kp)[2 * i8];
      float4 vb = ((const float4*)Kp)[2 * i8 + 1];
      bf16x8 o = {(__bf16)va.x, (__bf16)va.y, (__bf16)va.z, (__bf16)va.w,
                  (__bf16)vb.x, (__bf16)vb.y, (__bf16)vb.z, (__bf16)vb.w};
      ((bf16x8*)Kb)[i8] = o;
    }
  } else if (b < 4096) {
    __shared__ float tile[64][65];
    const int bb = b - 3072;
    const int bx = bb & 63, by = bb >> 6;
    for (int i = t; i < 64 * 64; i += 256) {
      const int r = i >> 6, c = i & 63;
      tile[r][c] = V[(size_t)(bx * 64 + r) * 1024 + by * 64 + c];
    }
    __syncthreads();
    for (int i = t; i < 64 * 64; i += 256) {
      const int r = i >> 6, c = i & 63;
      Vt[(size_t)(by * 64 + r) * 4096 + bx * 64 + c] = (__bf16)tile[c][r];
    }
  } else {
#pragma unroll
    for (int k = 0; k < 8; ++k)
      ((floatx4*)lsum)[k * 256 + t] = floatx4{0.f, 0.f, 0.f, 0.f};
  }
}

// C = A (MxK bf16, k-contig) x B (N rows of K bf16, k-contig). 128x128 tile, BK=64.
// m97-style staging: global_load_lds_dwordx4 direct to LDS (no VGPR round-trip,
// no ds_write on the critical path). Single LDS buffer, 2 barriers per K-step;
// the first __syncthreads' vmcnt(0) drain lands the async loads before ds_read.
// Latency hiding comes from multi-block residency (32 KiB LDS, 92 VGPR -> ~5
// blocks/CU; m114 wave-level overlap), NOT intra-block pipelining -- verified:
// R2-R4's 256x256 deep-pipeline variants all regressed to ~670 TF vs this 707.
// LDS: XOR-swizzled; 16-B unit (row m, k-chunk q in 0..7) at unit 8m + (q^(m&7)).
//  - LDS dest is LINEAR (thread t -> byte t*16 + r*4096); swizzle applied on the
//    GLOBAL source: thread t fetches row (t>>3), chunk (t&7)^((t>>3)&7).
//  - fragment reads conflict-free (verified: SQ_LDS_BANK_CONFLICT = 0).
//  - k-slice 1 address = slice-0 address ^ 64.
// Flat-1D grid + XCD swizzle (id%8 = XCD): blocks sharing an A m-tile share an XCD.
// MODE 0: P = exp(min(dot/32,30)) -> bf16 Cb + fused row-sum atomicAdd into lsum.
// MODE 1: out = dot / lsum[m] -> fp32 Cf.
template <int MODE, int KS, int NS>
__global__ __launch_bounds__(256) void gemm_kernel(const __bf16* __restrict__ A,
                                                   const __bf16* __restrict__ B,
                                                   __bf16* __restrict__ Cb,
                                                   float* __restrict__ Cf,
                                                   float* __restrict__ lsum) {
  constexpr int BK = 64;
  __shared__ __bf16 As[128 * BK];  // 16 KiB
  __shared__ __bf16 Bs[128 * BK];  // 16 KiB
  const int t = threadIdx.x;
  const int lane = t & 63;
  const int w = t >> 6;
  const int wr = w >> 1, wc = w & 1;

  const int id = blockIdx.x;
  const int g = id & 7;
  const int s = id >> 3;
  const int mt = g * 8 + (s & 7);
  const int nt = s >> 3;
  const int m0 = mt * 128;
  const int n0 = nt * 128;

  const __bf16* Ab = A + (size_t)m0 * KS;
  const __bf16* Bb = B + (size_t)n0 * KS;

  floatx4 acc[4][4] = {};

  // staging: thread t -> row r*32 + (t>>3), global chunk (t&7)^((t>>3)&7),
  // LDS dest byte t*16 + r*4096 (linear).
  const int mA = t >> 3;
  const int qs = (t & 7) ^ (mA & 7);
  const __bf16* aP = Ab + (size_t)mA * KS + qs * 8;
  const __bf16* bP = Bb + (size_t)mA * KS + qs * 8;
  char* dA = (char*)As + t * 16;
  char* dB = (char*)Bs + t * 16;

  // fragment read offset (k-slice 0)
  const int rl = lane & 15;
  const int qq = lane >> 4;
  const int fo = rl * 128 + ((qq ^ (rl & 7)) << 4);

  for (int k0 = 0; k0 < KS; k0 += BK) {
    // async stage tile k0 directly into LDS (8x global_load_lds_dwordx4)
#pragma unroll
    for (int r = 0; r < 4; ++r) {
      async16(dA + r * 4096, aP + (size_t)r * 32 * KS + k0);
      async16(dB + r * 4096, bP + (size_t)r * 32 * KS + k0);
    }
    __syncthreads();  // vmcnt(0)+lgkmcnt(0) drain: LDS image complete

    bf16x8 aF[4], bF[4];
#pragma unroll
    for (int i = 0; i < 4; ++i) {
      aF[i] = *(const bf16x8*)((const char*)As + wr * 8192 + i * 2048 + fo);
      bF[i] = *(const bf16x8*)((const char*)Bs + wc * 8192 + i * 2048 + fo);
    }
#pragma unroll
    for (int i = 0; i < 4; ++i)
#pragma unroll
      for (int j = 0; j < 4; ++j)
        acc[i][j] = __builtin_amdgcn_mfma_f32_16x16x32_bf16(aF[i], bF[j], acc[i][j], 0, 0, 0);
#pragma unroll
    for (int i = 0; i < 4; ++i) {
      aF[i] = *(const bf16x8*)((const char*)As + wr * 8192 + i * 2048 + (fo ^ 64));
      bF[i] = *(const bf16x8*)((const char*)Bs + wc * 8192 + i * 2048 + (fo ^ 64));
    }
#pragma unroll
    for (int i = 0; i < 4; ++i)
#pragma unroll
      for (int j = 0; j < 4; ++j)
        acc[i][j] = __builtin_amdgcn_mfma_f32_16x16x32_bf16(aF[i], bF[j], acc[i][j], 0, 0, 0);
    __syncthreads();  // protect LDS before next iteration's async stores land
  }

  // C/D layout: col = lane&15, row = (lane>>4)*4 + reg
  const int cm = wr * 64 + ((lane >> 4) << 2);
  const int cn = wc * 64 + (lane & 15);
  if (MODE == 0) {
#pragma unroll
    for (int i = 0; i < 4; ++i)
#pragma unroll
      for (int r = 0; r < 4; ++r) {
        const int m = m0 + cm + i * 16 + r;
        float rs = 0.f;
#pragma unroll
        for (int j = 0; j < 4; ++j) {
          const float e = __expf(fminf(acc[i][j][r] * 0.03125f, 30.0f));
          rs += e;
          Cb[(size_t)m * NS + n0 + cn + j * 16] = (__bf16)e;
        }
        rs += __shfl_xor(rs, 1, 64);
        rs += __shfl_xor(rs, 2, 64);
        rs += __shfl_xor(rs, 4, 64);
        rs += __shfl_xor(rs, 8, 64);
        if ((lane & 15) == 0) atomicAdd(&lsum[m], rs);
      }
  } else {
#pragma unroll
    for (int i = 0; i < 4; ++i)
#pragma unroll
      for (int r = 0; r < 4; ++r) {
        const int m = m0 + cm + i * 16 + r;
        const float inv = 1.0f / lsum[m];
#pragma unroll
        for (int j = 0; j < 4; ++j)
          Cf[(size_t)m * NS + n0 + cn + j * 16] = acc[i][j][r] * inv;
      }
  }
}

extern "C" void kernel_launch(void* const* d_in, const int* in_sizes, int n_in,
                              void* d_out, int out_size, void* d_ws, size_t ws_size,
                              hipStream_t stream) {
  const float* x = (const float*)d_in[0];  // [8192][1024] fp32
  const float* K = (const float*)d_in[1];  // [4096][1024] fp32
  const float* V = (const float*)d_in[2];  // [4096][1024] fp32
  float* out = (float*)d_out;              // [8192][1024] fp32

  char* ws = (char*)d_ws;
  __bf16* xb = (__bf16*)ws;                        // 16 MiB
  __bf16* Kb = (__bf16*)(ws + (16u << 20));        // 8 MiB
  __bf16* Vt = (__bf16*)(ws + (24u << 20));        // 8 MiB
  __bf16* P  = (__bf16*)(ws + (32u << 20));        // 64 MiB
  float*  l  = (float*)(ws + (96u << 20));         // 32 KiB

  preprocess_kernel<<<4097, 256, 0, stream>>>(x, K, V, xb, Kb, Vt, l);
  // P = exp(xb @ Kb^T / 32), fused row sums  (M=8192 N=4096 K=1024), 2048 blocks
  gemm_kernel<0, 1024, 4096><<<2048, 256, 0, stream>>>(xb, Kb, P, nullptr, l);
  // out = (P @ Vt-rows) / l  (M=8192 N=1024 K=4096), 512 blocks
  gemm_kernel<1, 4096, 1024><<<512, 256, 0, stream>>>(P, Vt, nullptr, out, l);
}

// Round 6
// 260.135 us; speedup vs baseline: 1.1146x; 1.0025x over previous
//
#include <hip/hip_runtime.h>
#include <hip/hip_bf16.h>

typedef __bf16 bf16x8 __attribute__((ext_vector_type(8)));
typedef __bf16 bf16x4 __attribute__((ext_vector_type(4)));
typedef float floatx4 __attribute__((ext_vector_type(4)));

// Async global->LDS DMA, 16 B per lane. Dest is wave-uniform base + lane*16
// (HW takes firstlane of the LDS pointer); source is per-lane.
__device__ __forceinline__ void async16(void* lds, const void* g) {
  __builtin_amdgcn_global_load_lds(
      (const __attribute__((address_space(1))) unsigned int*)g,
      (__attribute__((address_space(3))) unsigned int*)lds, 16, 0, 0);
}

// Fused preprocess: x->bf16 (blocks 0..2047), K->bf16 (2048..3071),
// V->Vt bf16 transpose (3072..4095), lsum zero (block 4096).
// All paths vectorized: 16 B global stores everywhere (Common-mistake #2 fix;
// the old transpose did 4096 scalar 2-B stores per block ~= 45 us of waste).
__global__ __launch_bounds__(256) void preprocess_kernel(
    const float* __restrict__ x, const float* __restrict__ Kp,
    const float* __restrict__ V, __bf16* __restrict__ xb,
    __bf16* __restrict__ Kb, __bf16* __restrict__ Vt,
    float* __restrict__ lsum) {
  const int b = blockIdx.x;
  const int t = threadIdx.x;
  if (b < 2048) {
#pragma unroll
    for (int k = 0; k < 2; ++k) {
      const int i8 = b * 512 + k * 256 + t;  // bf16x8 units
      float4 va = ((const float4*)x)[2 * i8];
      float4 vb = ((const float4*)x)[2 * i8 + 1];
      bf16x8 o = {(__bf16)va.x, (__bf16)va.y, (__bf16)va.z, (__bf16)va.w,
                  (__bf16)vb.x, (__bf16)vb.y, (__bf16)vb.z, (__bf16)vb.w};
      ((bf16x8*)xb)[i8] = o;
    }
  } else if (b < 3072) {
#pragma unroll
    for (int k = 0; k < 2; ++k) {
      const int i8 = (b - 2048) * 512 + k * 256 + t;
      float4 va = ((const float4*)Kp)[2 * i8];
      float4 vb = ((const float4*)Kp)[2 * i8 + 1];
      bf16x8 o = {(__bf16)va.x, (__bf16)va.y, (__bf16)va.z, (__bf16)va.w,
                  (__bf16)vb.x, (__bf16)vb.y, (__bf16)vb.z, (__bf16)vb.w};
      ((bf16x8*)Kb)[i8] = o;
    }
  } else if (b < 4096) {
    // V 64x64 tile transpose: Vt[e][p] = V[p][e].
    // Stage: float4 loads (coalesced 256B rows), scalar LDS writes at
    // stride 65 (banks (r+4k+j)%32: 2-way = free). Read-out: 8 params down a
    // column (banks (8s+j+e)%32: 2-way = free), pack bf16x8, 16 B store.
    __shared__ float tile[64][65];  // [param][emb], +1 pad
    const int bb = b - 3072;
    const int bx = bb & 63, by = bb >> 6;  // bx: param-tile, by: emb-tile
#pragma unroll
    for (int k = 0; k < 4; ++k) {
      const int i = k * 256 + t;
      const int r = i >> 4, c4 = (i & 15) << 2;  // r: param row, c4: emb col
      float4 v = *(const float4*)&V[(size_t)(bx * 64 + r) * 1024 + by * 64 + c4];
      tile[r][c4] = v.x; tile[r][c4 + 1] = v.y;
      tile[r][c4 + 2] = v.z; tile[r][c4 + 3] = v.w;
    }
    __syncthreads();
#pragma unroll
    for (int k = 0; k < 2; ++k) {
      const int i = k * 256 + t;
      const int e = i >> 3, sg = (i & 7) << 3;  // e: emb row of Vt, sg: param seg
      bf16x8 o;
#pragma unroll
      for (int j = 0; j < 8; ++j) o[j] = (__bf16)tile[sg + j][e];
      *(bf16x8*)&Vt[(size_t)(by * 64 + e) * 4096 + bx * 64 + sg] = o;
    }
  } else {
#pragma unroll
    for (int k = 0; k < 8; ++k)
      ((floatx4*)lsum)[k * 256 + t] = floatx4{0.f, 0.f, 0.f, 0.f};
  }
}

// C = A (MxK bf16, k-contig) x B (N rows of K bf16, k-contig). 128x128 tile, BK=64.
// m97-style staging: global_load_lds_dwordx4 direct to LDS (no VGPR round-trip,
// no ds_write on the critical path). Single LDS buffer, 2 barriers per K-step;
// the first __syncthreads' vmcnt(0) drain lands the async loads before ds_read.
// Latency hiding comes from multi-block residency (32 KiB LDS, 92 VGPR -> ~5
// blocks/CU; m114 wave-level overlap), NOT intra-block pipelining -- verified:
// R2-R4's 256x256 deep-pipeline variants all regressed to ~670 TF vs this 707.
// LDS: XOR-swizzled; 16-B unit (row m, k-chunk q in 0..7) at unit 8m + (q^(m&7)).
//  - LDS dest is LINEAR (thread t -> byte t*16 + r*4096); swizzle applied on the
//    GLOBAL source: thread t fetches row (t>>3), chunk (t&7)^((t>>3)&7).
//  - fragment reads conflict-free (verified: SQ_LDS_BANK_CONFLICT = 0).
//  - k-slice 1 address = slice-0 address ^ 64.
// Flat-1D grid + XCD swizzle (id%8 = XCD): blocks sharing an A m-tile share an XCD.
// MODE 0: P = exp(min(dot/32,30)) -> bf16 Cb + fused row-sum atomicAdd into lsum.
// MODE 1: out = dot / lsum[m] -> fp32 Cf.
template <int MODE, int KS, int NS>
__global__ __launch_bounds__(256) void gemm_kernel(const __bf16* __restrict__ A,
                                                   const __bf16* __restrict__ B,
                                                   __bf16* __restrict__ Cb,
                                                   float* __restrict__ Cf,
                                                   float* __restrict__ lsum) {
  constexpr int BK = 64;
  __shared__ __bf16 As[128 * BK];  // 16 KiB
  __shared__ __bf16 Bs[128 * BK];  // 16 KiB
  const int t = threadIdx.x;
  const int lane = t & 63;
  const int w = t >> 6;
  const int wr = w >> 1, wc = w & 1;

  const int id = blockIdx.x;
  const int g = id & 7;
  const int s = id >> 3;
  const int mt = g * 8 + (s & 7);
  const int nt = s >> 3;
  const int m0 = mt * 128;
  const int n0 = nt * 128;

  const __bf16* Ab = A + (size_t)m0 * KS;
  const __bf16* Bb = B + (size_t)n0 * KS;

  floatx4 acc[4][4] = {};

  // staging: thread t -> row r*32 + (t>>3), global chunk (t&7)^((t>>3)&7),
  // LDS dest byte t*16 + r*4096 (linear).
  const int mA = t >> 3;
  const int qs = (t & 7) ^ (mA & 7);
  const __bf16* aP = Ab + (size_t)mA * KS + qs * 8;
  const __bf16* bP = Bb + (size_t)mA * KS + qs * 8;
  char* dA = (char*)As + t * 16;
  char* dB = (char*)Bs + t * 16;

  // fragment read offset (k-slice 0)
  const int rl = lane & 15;
  const int qq = lane >> 4;
  const int fo = rl * 128 + ((qq ^ (rl & 7)) << 4);

  for (int k0 = 0; k0 < KS; k0 += BK) {
    // async stage tile k0 directly into LDS (8x global_load_lds_dwordx4)
#pragma unroll
    for (int r = 0; r < 4; ++r) {
      async16(dA + r * 4096, aP + (size_t)r * 32 * KS + k0);
      async16(dB + r * 4096, bP + (size_t)r * 32 * KS + k0);
    }
    __syncthreads();  // vmcnt(0)+lgkmcnt(0) drain: LDS image complete

    bf16x8 aF[4], bF[4];
#pragma unroll
    for (int i = 0; i < 4; ++i) {
      aF[i] = *(const bf16x8*)((const char*)As + wr * 8192 + i * 2048 + fo);
      bF[i] = *(const bf16x8*)((const char*)Bs + wc * 8192 + i * 2048 + fo);
    }
#pragma unroll
    for (int i = 0; i < 4; ++i)
#pragma unroll
      for (int j = 0; j < 4; ++j)
        acc[i][j] = __builtin_amdgcn_mfma_f32_16x16x32_bf16(aF[i], bF[j], acc[i][j], 0, 0, 0);
#pragma unroll
    for (int i = 0; i < 4; ++i) {
      aF[i] = *(const bf16x8*)((const char*)As + wr * 8192 + i * 2048 + (fo ^ 64));
      bF[i] = *(const bf16x8*)((const char*)Bs + wc * 8192 + i * 2048 + (fo ^ 64));
    }
#pragma unroll
    for (int i = 0; i < 4; ++i)
#pragma unroll
      for (int j = 0; j < 4; ++j)
        acc[i][j] = __builtin_amdgcn_mfma_f32_16x16x32_bf16(aF[i], bF[j], acc[i][j], 0, 0, 0);
    __syncthreads();  // protect LDS before next iteration's async stores land
  }

  // C/D layout: col = lane&15, row = (lane>>4)*4 + reg
  const int cm = wr * 64 + ((lane >> 4) << 2);
  const int cn = wc * 64 + (lane & 15);
  if (MODE == 0) {
#pragma unroll
    for (int i = 0; i < 4; ++i)
#pragma unroll
      for (int r = 0; r < 4; ++r) {
        const int m = m0 + cm + i * 16 + r;
        float rs = 0.f;
#pragma unroll
        for (int j = 0; j < 4; ++j) {
          const float e = __expf(fminf(acc[i][j][r] * 0.03125f, 30.0f));
          rs += e;
          Cb[(size_t)m * NS + n0 + cn + j * 16] = (__bf16)e;
        }
        rs += __shfl_xor(rs, 1, 64);
        rs += __shfl_xor(rs, 2, 64);
        rs += __shfl_xor(rs, 4, 64);
        rs += __shfl_xor(rs, 8, 64);
        if ((lane & 15) == 0) atomicAdd(&lsum[m], rs);
      }
  } else {
#pragma unroll
    for (int i = 0; i < 4; ++i)
#pragma unroll
      for (int r = 0; r < 4; ++r) {
        const int m = m0 + cm + i * 16 + r;
        const float inv = 1.0f / lsum[m];
#pragma unroll
        for (int j = 0; j < 4; ++j)
          Cf[(size_t)m * NS + n0 + cn + j * 16] = acc[i][j][r] * inv;
      }
  }
}

extern "C" void kernel_launch(void* const* d_in, const int* in_sizes, int n_in,
                              void* d_out, int out_size, void* d_ws, size_t ws_size,
                              hipStream_t stream) {
  const float* x = (const float*)d_in[0];  // [8192][1024] fp32
  const float* K = (const float*)d_in[1];  // [4096][1024] fp32
  const float* V = (const float*)d_in[2];  // [4096][1024] fp32
  float* out = (float*)d_out;              // [8192][1024] fp32

  char* ws = (char*)d_ws;
  __bf16* xb = (__bf16*)ws;                        // 16 MiB
  __bf16* Kb = (__bf16*)(ws + (16u << 20));        // 8 MiB
  __bf16* Vt = (__bf16*)(ws + (24u << 20));        // 8 MiB
  __bf16* P  = (__bf16*)(ws + (32u << 20));        // 64 MiB
  float*  l  = (float*)(ws + (96u << 20));         // 32 KiB

  preprocess_kernel<<<4097, 256, 0, stream>>>(x, K, V, xb, Kb, Vt, l);
  // P = exp(xb @ Kb^T / 32), fused row sums  (M=8192 N=4096 K=1024), 2048 blocks
  gemm_kernel<0, 1024, 4096><<<2048, 256, 0, stream>>>(xb, Kb, P, nullptr, l);
  // out = (P @ Vt-rows) / l  (M=8192 N=1024 K=4096), 512 blocks
  gemm_kernel<1, 4096, 1024><<<512, 256, 0, stream>>>(P, Vt, nullptr, out, l);
}

// Round 7
// 259.492 us; speedup vs baseline: 1.1174x; 1.0025x over previous
//
#include <hip/hip_runtime.h>
#include <hip/hip_bf16.h>

typedef __bf16 bf16x8 __attribute__((ext_vector_type(8)));
typedef __bf16 bf16x4 __attribute__((ext_vector_type(4)));
typedef float floatx4 __attribute__((ext_vector_type(4)));

// Async global->LDS DMA, 16 B per lane. Dest is wave-uniform base + lane*16
// (HW takes firstlane of the LDS pointer); source is per-lane.
__device__ __forceinline__ void async16(void* lds, const void* g) {
  __builtin_amdgcn_global_load_lds(
      (const __attribute__((address_space(1))) unsigned int*)g,
      (__attribute__((address_space(3))) unsigned int*)lds, 16, 0, 0);
}

// Preprocess: x->bf16 (blocks 0..2047), K->bf16 (2048..3071), lsum zero (3072).
// V-transpose moved INTO gemm_kernel<0>'s grid (its output Vt is only needed
// by GEMM2, so it overlaps GEMM1's tail round for free).
__global__ __launch_bounds__(256) void preprocess_kernel(
    const float* __restrict__ x, const float* __restrict__ Kp,
    __bf16* __restrict__ xb, __bf16* __restrict__ Kb,
    float* __restrict__ lsum) {
  const int b = blockIdx.x;
  const int t = threadIdx.x;
  if (b < 2048) {
#pragma unroll
    for (int k = 0; k < 2; ++k) {
      const int i8 = b * 512 + k * 256 + t;  // bf16x8 units
      float4 va = ((const float4*)x)[2 * i8];
      float4 vb = ((const float4*)x)[2 * i8 + 1];
      bf16x8 o = {(__bf16)va.x, (__bf16)va.y, (__bf16)va.z, (__bf16)va.w,
                  (__bf16)vb.x, (__bf16)vb.y, (__bf16)vb.z, (__bf16)vb.w};
      ((bf16x8*)xb)[i8] = o;
    }
  } else if (b < 3072) {
#pragma unroll
    for (int k = 0; k < 2; ++k) {
      const int i8 = (b - 2048) * 512 + k * 256 + t;
      float4 va = ((const float4*)Kp)[2 * i8];
      float4 vb = ((const float4*)Kp)[2 * i8 + 1];
      bf16x8 o = {(__bf16)va.x, (__bf16)va.y, (__bf16)va.z, (__bf16)va.w,
                  (__bf16)vb.x, (__bf16)vb.y, (__bf16)vb.z, (__bf16)vb.w};
      ((bf16x8*)Kb)[i8] = o;
    }
  } else {
#pragma unroll
    for (int k = 0; k < 8; ++k)
      ((floatx4*)lsum)[k * 256 + t] = floatx4{0.f, 0.f, 0.f, 0.f};
  }
}

// C = A (MxK bf16, k-contig) x B (N rows of K bf16, k-contig). 128x128 tile, BK=64.
// m97-style staging: global_load_lds_dwordx4 direct to LDS. Single LDS buffer,
// 2 barriers per K-step. Latency hiding via multi-block residency (32 KiB LDS,
// 92 VGPR -> 5 blocks/CU; m114 wave-level overlap) -- R2-R4's deep-pipeline
// variants all regressed vs this structure.
// LDS: XOR-swizzled; 16-B unit (row m, k-chunk q in 0..7) at unit 8m + (q^(m&7)).
//  - LDS dest LINEAR (t*16 + r*4096); swizzle applied on the GLOBAL source:
//    thread t fetches row (t>>3), chunk (t&7)^((t>>3)&7).
//  - fragment reads conflict-free (verified: SQ_LDS_BANK_CONFLICT = 0).
//  - k-slice 1 address = slice-0 address ^ 64.
// Flat-1D grid + XCD swizzle (id%8 = XCD) for ids < NB gemm blocks.
// MODE 0 extra blocks (id >= 2048): V 64x64-tile transpose Vt[e][p] = V[p][e]
// (fp32 loads -> LDS [64][65] -> bf16x8 stores), overlapping GEMM1's tail.
// MODE 0: P = exp(min(dot/32,30)) -> bf16 Cb + fused row-sum atomicAdd into lsum.
// MODE 1: out = dot / lsum[m] -> fp32 Cf.
template <int MODE, int KS, int NS>
__global__ __launch_bounds__(256) void gemm_kernel(const __bf16* __restrict__ A,
                                                   const __bf16* __restrict__ B,
                                                   __bf16* __restrict__ Cb,
                                                   float* __restrict__ Cf,
                                                   float* __restrict__ lsum,
                                                   const float* __restrict__ Vsrc,
                                                   __bf16* __restrict__ Vt) {
  constexpr int BK = 64;
  __shared__ __align__(16) char smem[32768];
  __bf16* As = (__bf16*)smem;            // 16 KiB
  __bf16* Bs = (__bf16*)(smem + 16384);  // 16 KiB
  const int t = threadIdx.x;
  const int id = blockIdx.x;

  if (MODE == 0 && id >= 2048) {
    // V transpose block (uniform branch; reuses the 32 KiB smem as fp32 tile)
    float(*tile)[65] = (float(*)[65])smem;  // 64*65*4 = 16.6 KiB
    const int bb = id - 2048;
    const int bx = bb & 63, by = bb >> 6;  // bx: param-tile, by: emb-tile
#pragma unroll
    for (int k = 0; k < 4; ++k) {
      const int i = k * 256 + t;
      const int r = i >> 4, c4 = (i & 15) << 2;  // r: param row, c4: emb col
      float4 v = *(const float4*)&Vsrc[(size_t)(bx * 64 + r) * 1024 + by * 64 + c4];
      tile[r][c4] = v.x; tile[r][c4 + 1] = v.y;
      tile[r][c4 + 2] = v.z; tile[r][c4 + 3] = v.w;
    }
    __syncthreads();
#pragma unroll
    for (int k = 0; k < 2; ++k) {
      const int i = k * 256 + t;
      const int e = i >> 3, sg = (i & 7) << 3;  // e: emb row of Vt, sg: param seg
      bf16x8 o;
#pragma unroll
      for (int j = 0; j < 8; ++j) o[j] = (__bf16)tile[sg + j][e];
      *(bf16x8*)&Vt[(size_t)(by * 64 + e) * 4096 + bx * 64 + sg] = o;
    }
    return;
  }

  const int lane = t & 63;
  const int w = t >> 6;
  const int wr = w >> 1, wc = w & 1;

  const int g = id & 7;
  const int s = id >> 3;
  const int mt = g * 8 + (s & 7);
  const int nt = s >> 3;
  const int m0 = mt * 128;
  const int n0 = nt * 128;

  const __bf16* Ab = A + (size_t)m0 * KS;
  const __bf16* Bb = B + (size_t)n0 * KS;

  floatx4 acc[4][4] = {};

  // staging: thread t -> row r*32 + (t>>3), global chunk (t&7)^((t>>3)&7),
  // LDS dest byte t*16 + r*4096 (linear).
  const int mA = t >> 3;
  const int qs = (t & 7) ^ (mA & 7);
  const __bf16* aP = Ab + (size_t)mA * KS + qs * 8;
  const __bf16* bP = Bb + (size_t)mA * KS + qs * 8;
  char* dA = (char*)As + t * 16;
  char* dB = (char*)Bs + t * 16;

  // fragment read offset (k-slice 0)
  const int rl = lane & 15;
  const int qq = lane >> 4;
  const int fo = rl * 128 + ((qq ^ (rl & 7)) << 4);

  for (int k0 = 0; k0 < KS; k0 += BK) {
    // async stage tile k0 directly into LDS (8x global_load_lds_dwordx4)
#pragma unroll
    for (int r = 0; r < 4; ++r) {
      async16(dA + r * 4096, aP + (size_t)r * 32 * KS + k0);
      async16(dB + r * 4096, bP + (size_t)r * 32 * KS + k0);
    }
    __syncthreads();  // vmcnt(0)+lgkmcnt(0) drain: LDS image complete

    bf16x8 aF[4], bF[4];
#pragma unroll
    for (int i = 0; i < 4; ++i) {
      aF[i] = *(const bf16x8*)((const char*)As + wr * 8192 + i * 2048 + fo);
      bF[i] = *(const bf16x8*)((const char*)Bs + wc * 8192 + i * 2048 + fo);
    }
#pragma unroll
    for (int i = 0; i < 4; ++i)
#pragma unroll
      for (int j = 0; j < 4; ++j)
        acc[i][j] = __builtin_amdgcn_mfma_f32_16x16x32_bf16(aF[i], bF[j], acc[i][j], 0, 0, 0);
#pragma unroll
    for (int i = 0; i < 4; ++i) {
      aF[i] = *(const bf16x8*)((const char*)As + wr * 8192 + i * 2048 + (fo ^ 64));
      bF[i] = *(const bf16x8*)((const char*)Bs + wc * 8192 + i * 2048 + (fo ^ 64));
    }
#pragma unroll
    for (int i = 0; i < 4; ++i)
#pragma unroll
      for (int j = 0; j < 4; ++j)
        acc[i][j] = __builtin_amdgcn_mfma_f32_16x16x32_bf16(aF[i], bF[j], acc[i][j], 0, 0, 0);
    __syncthreads();  // protect LDS before next iteration's async stores land
  }

  // C/D layout: col = lane&15, row = (lane>>4)*4 + reg
  const int cm = wr * 64 + ((lane >> 4) << 2);
  const int cn = wc * 64 + (lane & 15);
  if (MODE == 0) {
#pragma unroll
    for (int i = 0; i < 4; ++i)
#pragma unroll
      for (int r = 0; r < 4; ++r) {
        const int m = m0 + cm + i * 16 + r;
        float rs = 0.f;
#pragma unroll
        for (int j = 0; j < 4; ++j) {
          const float e = __expf(fminf(acc[i][j][r] * 0.03125f, 30.0f));
          rs += e;
          Cb[(size_t)m * NS + n0 + cn + j * 16] = (__bf16)e;
        }
        rs += __shfl_xor(rs, 1, 64);
        rs += __shfl_xor(rs, 2, 64);
        rs += __shfl_xor(rs, 4, 64);
        rs += __shfl_xor(rs, 8, 64);
        if ((lane & 15) == 0) atomicAdd(&lsum[m], rs);
      }
  } else {
#pragma unroll
    for (int i = 0; i < 4; ++i)
#pragma unroll
      for (int r = 0; r < 4; ++r) {
        const int m = m0 + cm + i * 16 + r;
        const float inv = 1.0f / lsum[m];
#pragma unroll
        for (int j = 0; j < 4; ++j)
          Cf[(size_t)m * NS + n0 + cn + j * 16] = acc[i][j][r] * inv;
      }
  }
}

extern "C" void kernel_launch(void* const* d_in, const int* in_sizes, int n_in,
                              void* d_out, int out_size, void* d_ws, size_t ws_size,
                              hipStream_t stream) {
  const float* x = (const float*)d_in[0];  // [8192][1024] fp32
  const float* K = (const float*)d_in[1];  // [4096][1024] fp32
  const float* V = (const float*)d_in[2];  // [4096][1024] fp32
  float* out = (float*)d_out;              // [8192][1024] fp32

  char* ws = (char*)d_ws;
  __bf16* xb = (__bf16*)ws;                        // 16 MiB
  __bf16* Kb = (__bf16*)(ws + (16u << 20));        // 8 MiB
  __bf16* Vt = (__bf16*)(ws + (24u << 20));        // 8 MiB
  __bf16* P  = (__bf16*)(ws + (32u << 20));        // 64 MiB
  float*  l  = (float*)(ws + (96u << 20));         // 32 KiB

  // x/K -> bf16, lsum zero (V-transpose rides inside GEMM1's grid)
  preprocess_kernel<<<3073, 256, 0, stream>>>(x, K, xb, Kb, l);
  // P = exp(xb @ Kb^T / 32) + row sums (M=8192 N=4096 K=1024), 2048 gemm blocks
  // + 1024 V-transpose blocks that fill GEMM1's tail round.
  gemm_kernel<0, 1024, 4096><<<3072, 256, 0, stream>>>(xb, Kb, P, nullptr, l, V, Vt);
  // out = (P @ Vt-rows) / l  (M=8192 N=1024 K=4096), 512 blocks
  gemm_kernel<1, 4096, 1024><<<512, 256, 0, stream>>>(P, Vt, nullptr, out, l, nullptr, nullptr);
}